// Round 5
// baseline (6124.207 us; speedup 1.0000x reference)
//
#include <hip/hip_runtime.h>
#include <math.h>

#define Hh 240
#define Ww 480
#define HW 115200      // Hh*Ww
#define Cc 128
#define Kk 1152        // Cc*9
#define HALFW 240      // Ww/2
#define NB_RED 1440

typedef unsigned int u32;
typedef __attribute__((address_space(3))) u32 lds_u32;
typedef const __attribute__((address_space(1))) u32 glb_u32;

// ---------------------------------------------------------------------------
// geo_pad-fused index: flat index into a [C][H][W] plane for padded coords
// (r in [-1,Hh], c in [-1,Ww]).
// ---------------------------------------------------------------------------
__device__ __forceinline__ int geo_index(int ch, int r, int c) {
    int wv = (c < 0) ? (Ww - 1) : ((c >= Ww) ? 0 : c);
    int rr;
    if (r < 0)        { rr = 0;      wv = (wv >= HALFW) ? wv - HALFW : wv + HALFW; }
    else if (r >= Hh) { rr = Hh - 1; wv = (wv >= HALFW) ? wv - HALFW : wv + HALFW; }
    else              { rr = r; }
    return (ch * Hh + rr) * Ww + wv;
}

__device__ __forceinline__ float padfetch(const float* __restrict__ p, int yi, int xj) {
    int r = yi - 1, c = xj - 1;
    int wv = (c < 0) ? (Ww - 1) : ((c >= Ww) ? 0 : c);
    int rr;
    if (r < 0)        { rr = 0;      wv = (wv >= HALFW) ? wv - HALFW : wv + HALFW; }
    else if (r >= Hh) { rr = Hh - 1; wv = (wv >= HALFW) ? wv - HALFW : wv + HALFW; }
    else              { rr = r; }
    return p[rr * Ww + wv];
}

// small-angle double sincos (|x| <~ 0.7), libm fallback — IDENTICAL to round 2
__device__ __forceinline__ void sincos_small(double x, double* s, double* c) {
    double x2 = x * x;
    if (x2 > 0.49) { *s = sin(x); *c = cos(x); return; }
    *s = x * (1.0 + x2 * (-1.6666666666666666e-1 + x2 * (8.3333333333333333e-3 +
         x2 * (-1.9841269841269841e-4 + x2 * (2.7557319223985893e-6 - x2 * 2.5052108385441720e-8)))));
    *c = 1.0 + x2 * (-0.5 + x2 * (4.1666666666666666e-2 + x2 * (-1.3888888888888889e-3 +
         x2 * (2.4801587301587302e-5 - x2 * 2.7557319223985893e-7))));
}

// ---------------------------------------------------------------------------
__global__ void transpose_w(const float* __restrict__ w, float* __restrict__ wT, int N) {
    int idx = blockIdx.x * 256 + threadIdx.x;      // idx = k*N + n
    if (idx >= N * Kk) return;
    int k = idx / N;
    int n = idx - k * N;
    wT[idx] = w[n * Kk + k];
}

// ---------------------------------------------------------------------------
// implicit-GEMM 3x3 conv, geo_pad fused into the gather.
// 128x128 tile, BK=16, 256 threads, 8x8 micro-tile.
// A AND B staged via global_load_lds, double-buffered; inner loop is pure
// ds_read+FMA. k-order per output identical to rounds 2-4 (bit-exact).
// LDS 32KB/block + VGPR<=128 (launch_bounds 4 waves/EU) -> 4 blocks/CU.
// ---------------------------------------------------------------------------
__global__ __launch_bounds__(256, 4)
void conv_gemm(const float* __restrict__ in,    // [Cc][HW] batch plane base
               const float* __restrict__ wT,    // [Kk][N]
               const float* __restrict__ bias,  // [N]
               float* __restrict__ out,         // [N][HW]
               int N)
{
    const int tid = threadIdx.x;
    const int tx = tid & 15;     // m
    const int ty = tid >> 4;     // n
    const int m0 = blockIdx.x * 128;
    const int n0 = blockIdx.y * 128;

    __shared__ float As[2][16][128];  // [buf][k][m]
    __shared__ float Bs[2][16][128];  // [buf][k][n]

    // staging identity: this thread stages column (tid&127), rows (tid>>7)+2i.
    // LDS dst = wave-uniform base (row, tid&64) + lane*4 (HW-imposed layout).
    const int ki0     = tid >> 7;
    const int colbase = tid & 64;            // wave-uniform
    const int m       = m0 + (tid & 127);
    const int h       = m / Ww;
    const int w       = m - h * Ww;

    float acc[8][8] = {};

    auto stageA = [&](int buf, int kt) {
        #pragma unroll
        for (int i = 0; i < 8; i++) {
            int k  = kt + ki0 + 2 * i;
            int ic = k / 9;
            int t9 = k - ic * 9;
            int kh = t9 / 3;
            int kw = t9 - kh * 3;
            int gidx = geo_index(ic, h + kh - 1, w + kw - 1);
            __builtin_amdgcn_global_load_lds(
                (glb_u32*)(in + gidx),
                (lds_u32*)&As[buf][ki0 + 2 * i][colbase],
                4, 0, 0);
        }
    };
    auto stageB = [&](int buf, int kt) {
        const float* src = wT + (size_t)(kt + ki0) * N + n0 + (tid & 127);
        #pragma unroll
        for (int i = 0; i < 8; i++) {
            __builtin_amdgcn_global_load_lds(
                (glb_u32*)(src + (size_t)(2 * i) * N),
                (lds_u32*)&Bs[buf][ki0 + 2 * i][colbase],
                4, 0, 0);
        }
    };

    stageA(0, 0);
    stageB(0, 0);
    __syncthreads();

    int buf = 0;
    for (int kt = 0; kt < Kk; kt += 16) {
        if (kt + 16 < Kk) { stageA(buf ^ 1, kt + 16); stageB(buf ^ 1, kt + 16); }
        #pragma unroll
        for (int kk = 0; kk < 16; kk++) {
            float4 a0 = *(const float4*)&As[buf][kk][tx * 4];
            float4 a1 = *(const float4*)&As[buf][kk][64 + tx * 4];
            float4 b0 = *(const float4*)&Bs[buf][kk][ty * 4];
            float4 b1 = *(const float4*)&Bs[buf][kk][64 + ty * 4];
            float av[8] = {a0.x, a0.y, a0.z, a0.w, a1.x, a1.y, a1.z, a1.w};
            float bv[8] = {b0.x, b0.y, b0.z, b0.w, b1.x, b1.y, b1.z, b1.w};
            #pragma unroll
            for (int i = 0; i < 8; i++)
                #pragma unroll
                for (int j = 0; j < 8; j++)
                    acc[i][j] = fmaf(av[i], bv[j], acc[i][j]);
        }
        __syncthreads();
        buf ^= 1;
    }

    #pragma unroll
    for (int hn = 0; hn < 2; hn++)
        #pragma unroll
        for (int j = 0; j < 4; j++) {
            int n = n0 + hn * 64 + ty * 4 + j;
            float bv = bias[n];
            #pragma unroll
            for (int hm = 0; hm < 2; hm++) {
                float4 o;
                o.x = acc[hm * 4 + 0][hn * 4 + j] + bv;
                o.y = acc[hm * 4 + 1][hn * 4 + j] + bv;
                o.z = acc[hm * 4 + 2][hn * 4 + j] + bv;
                o.w = acc[hm * 4 + 3][hn * 4 + j] + bv;
                *(float4*)&out[(size_t)n * HW + m0 + hm * 64 + tx * 4] = o;
            }
        }
}

// ---------------------------------------------------------------------------
// deterministic two-stage LayerNorm stats
// ---------------------------------------------------------------------------
__global__ __launch_bounds__(256)
void reduce_stats(const float* __restrict__ y, float* __restrict__ part) {
    const int n4 = (Cc * HW) / 4;
    float s = 0.f, ss = 0.f;
    for (int i = blockIdx.x * 256 + threadIdx.x; i < n4; i += NB_RED * 256) {
        float4 v = ((const float4*)y)[i];
        s  += v.x + v.y + v.z + v.w;
        ss += v.x * v.x + v.y * v.y + v.z * v.z + v.w * v.w;
    }
    #pragma unroll
    for (int o = 32; o > 0; o >>= 1) { s += __shfl_down(s, o); ss += __shfl_down(ss, o); }
    __shared__ float ls[4], lss[4];
    int wid = threadIdx.x >> 6, lane = threadIdx.x & 63;
    if (lane == 0) { ls[wid] = s; lss[wid] = ss; }
    __syncthreads();
    if (threadIdx.x == 0) {
        part[blockIdx.x * 2]     = ls[0] + ls[1] + ls[2] + ls[3];
        part[blockIdx.x * 2 + 1] = lss[0] + lss[1] + lss[2] + lss[3];
    }
}

__global__ __launch_bounds__(256)
void finalize_stats(const float* __restrict__ part, float* __restrict__ stats) {
    float s = 0.f, ss = 0.f;
    for (int i = threadIdx.x; i < NB_RED; i += 256) { s += part[2 * i]; ss += part[2 * i + 1]; }
    #pragma unroll
    for (int o = 32; o > 0; o >>= 1) { s += __shfl_down(s, o); ss += __shfl_down(ss, o); }
    __shared__ float ls[4], lss[4];
    int wid = threadIdx.x >> 6, lane = threadIdx.x & 63;
    if (lane == 0) { ls[wid] = s; lss[wid] = ss; }
    __syncthreads();
    if (threadIdx.x == 0) {
        stats[0] = ls[0] + ls[1] + ls[2] + ls[3];
        stats[1] = lss[0] + lss[1] + lss[2] + lss[3];
    }
}

__global__ void norm_silu(float* __restrict__ y, const float* __restrict__ g,
                          const float* __restrict__ bb, const float* __restrict__ stats) {
    int i = blockIdx.x * 256 + threadIdx.x;
    if (i >= Cc * HW) return;
    const float invN = 1.f / (float)(Cc * HW);
    float mu  = stats[0] * invN;
    float var = stats[1] * invN - mu * mu;
    float inv = rsqrtf(var + 1e-5f);
    float z = (y[i] - mu) * inv * g[i] + bb[i];
    y[i] = z / (1.f + expf(-z));
}

// ---------------------------------------------------------------------------
__global__ void pix_trig(const float* __restrict__ latg, double* __restrict__ sphid) {
    int m = blockIdx.x * 256 + threadIdx.x;
    if (m >= HW) return;
    double phi = (double)latg[m];
    sphid[m]      = sin(phi);
    sphid[HW + m] = cos(phi);
}

// ---------------------------------------------------------------------------
// departure-point trig + bicubic sample. Hybrid precision: fp32 fast path for
// low-amplification pixels; bit-identical-to-round-2 fp64 path otherwise.
// ---------------------------------------------------------------------------
__global__ __launch_bounds__(256)
void semilag(const float* __restrict__ vel,     // [2*Cc][HW] batch base
             const float* __restrict__ hid,     // [Cc][HW] batch base
             const double* __restrict__ sphid,  // [2][HW] sin/cos(lat)
             const float* __restrict__ lng,     // [HW]
             const float* __restrict__ dtp,
             float* __restrict__ out)           // [Cc][HW] batch base
{
    int idx = blockIdx.x * 256 + threadIdx.x;
    if (idx >= Cc * HW) return;
    int c = idx / HW;
    int m = idx - c * HW;

    const double TWO_PI = 6.2831853071795864769252867665590;
    const double PI_D   = 3.1415926535897932384626433832795;
    const float  PI2F   = 6.28318530717958647692f;

    float uf = vel[idx];
    float vf = vel[Cc * HW + idx];
    float dtf = dtp[0];
    double sphi_d = sphid[m], cphi_d = sphid[HW + m];
    float lam_f = lng[m];

    // ---- fp32 gate evaluation ----
    float lonp_f = -uf * dtf, latp_f = -vf * dtf;
    float slp_f = sinf(latp_f), clp_f = cosf(latp_f);
    float slo_f = sinf(lonp_f), clo_f = cosf(lonp_f);
    float sphi_f = (float)sphi_d, cphi_f = (float)cphi_d;
    float sinlat_f = slp_f * cphi_f + clp_f * clo_f * sphi_f;
    float num_f = clp_f * slo_f;
    float den_f = clp_f * clo_f * cphi_f - slp_f * sphi_f;
    float r2_f  = num_f * num_f + den_f * den_f;

    float lon_w = lam_f + atan2f(num_f, den_f) + PI2F;
    lon_w = lon_w - floorf(lon_w / PI2F) * PI2F;
    float seam = fminf(lon_w, PI2F - lon_w);

    bool fast = (cphi_f > 0.2f) & (r2_f > 0.01f) & (fabsf(sinlat_f) < 0.98f) & (seam > 1e-4f);

    double ixd, iyd;
    if (fast) {
        float sl = fminf(fmaxf(sinlat_f, -1.f + 1e-7f), 1.f - 1e-7f);
        float lat_dep = asinf(sl);
        float gx = (lon_w / PI2F * 2.f - 1.f) * (480.f / 482.f);
        float gy = (lat_dep / 3.14159265358979323846f * 2.f - 1.f) * (240.f / 242.f);
        ixd = (double)fminf(fmaxf((gx + 1.f) * 0.5f * 481.f, 0.f), 481.f);
        iyd = (double)fminf(fmaxf((gy + 1.f) * 0.5f * 241.f, 0.f), 241.f);
    } else {
        // ---- fp64 path: IDENTICAL arithmetic to round 2 ----
        double dt = (double)dtf;
        double u = (double)uf;
        double v = (double)vf;
        double lonp = -u * dt, latp = -v * dt;
        double slp, clp, slo, clo;
        sincos_small(latp, &slp, &clp);
        sincos_small(lonp, &slo, &clo);
        double sphi = sphi_d, cphi = cphi_d;

        double sinlat = slp * cphi + clp * clo * sphi;
        sinlat = fmin(fmax(sinlat, -1.0 + 1e-7), 1.0 - 1e-7);
        double lat_dep = asin(sinlat);

        double num = clp * slo;
        double den = clp * clo * cphi - slp * sphi;
        double lon_dep = (double)lam_f + atan2(num, den);
        double xr = lon_dep + TWO_PI;
        xr = xr - floor(xr / TWO_PI) * TWO_PI;

        double gx = (xr / TWO_PI * 2.0 - 1.0) * (480.0 / 482.0);
        double gy = (lat_dep / PI_D * 2.0 - 1.0) * (240.0 / 242.0);

        ixd = fmin(fmax((gx + 1.0) * 0.5 * 481.0, 0.0), 481.0);
        iyd = fmin(fmax((gy + 1.0) * 0.5 * 241.0, 0.0), 241.0);
    }

    double x0d = floor(ixd), y0d = floor(iyd);
    float fx = (float)(ixd - x0d), fy = (float)(iyd - y0d);
    int x0 = (int)x0d, y0 = (int)y0d;

    const float a = -0.75f;
    float wx[4], wy[4];
    {
        float t = fx;
        float t1 = 1.f + t, t2 = 2.f - t, s1 = 1.f - t;
        wx[0] = ((a * t1 - 5.f * a) * t1 + 8.f * a) * t1 - 4.f * a;
        wx[1] = ((a + 2.f) * t - (a + 3.f)) * t * t + 1.f;
        wx[2] = ((a + 2.f) * s1 - (a + 3.f)) * s1 * s1 + 1.f;
        wx[3] = ((a * t2 - 5.f * a) * t2 + 8.f * a) * t2 - 4.f * a;
        t = fy;
        t1 = 1.f + t; t2 = 2.f - t; s1 = 1.f - t;
        wy[0] = ((a * t1 - 5.f * a) * t1 + 8.f * a) * t1 - 4.f * a;
        wy[1] = ((a + 2.f) * t - (a + 3.f)) * t * t + 1.f;
        wy[2] = ((a + 2.f) * s1 - (a + 3.f)) * s1 * s1 + 1.f;
        wy[3] = ((a * t2 - 5.f * a) * t2 + 8.f * a) * t2 - 4.f * a;
    }

    const float* plane = hid + (size_t)c * HW;
    float accv = 0.f;
    #pragma unroll
    for (int i = 0; i < 4; i++) {
        int yi = min(max(y0 + i - 1, 0), 241);
        float row = 0.f;
        #pragma unroll
        for (int j = 0; j < 4; j++) {
            int xj = min(max(x0 + j - 1, 0), 481);
            row = fmaf(wx[j], padfetch(plane, yi, xj), row);
        }
        accv = fmaf(wy[i], row, accv);
    }
    out[idx] = accv;
}

// ---------------------------------------------------------------------------
extern "C" void kernel_launch(void* const* d_in, const int* in_sizes, int n_in,
                              void* d_out, int out_size, void* d_ws, size_t ws_size,
                              hipStream_t stream)
{
    const float* hidden = (const float*)d_in[0];
    const float* latg   = (const float*)d_in[1];
    const float* lng    = (const float*)d_in[2];
    const float* w1     = (const float*)d_in[3];
    const float* b1     = (const float*)d_in[4];
    const float* g      = (const float*)d_in[5];
    const float* lb     = (const float*)d_in[6];
    const float* w2     = (const float*)d_in[7];
    const float* b2     = (const float*)d_in[8];
    const float* dt     = (const float*)d_in[9];
    float* out = (float*)d_out;

    // ws layout (floats): stats[4] | part[2880] | wT1 | wT2 | y1[C*HW] | vel[2C*HW]
    float* ws    = (float*)d_ws;
    float* stats = ws;
    float* part  = ws + 4;
    float* wT1   = part + 2 * NB_RED;
    float* wT2   = wT1 + Kk * Cc;
    float* y1    = wT2 + Kk * 2 * Cc;
    float* vel   = y1 + (size_t)Cc * HW;
    double* dbuf = (double*)y1;   // y1 region reused after conv2 (8B-aligned)

    transpose_w<<<(Cc * Kk + 255) / 256, 256, 0, stream>>>(w1, wT1, Cc);
    transpose_w<<<(2 * Cc * Kk + 255) / 256, 256, 0, stream>>>(w2, wT2, 2 * Cc);

    for (int b = 0; b < 2; b++) {
        const float* hb = hidden + (size_t)b * Cc * HW;
        conv_gemm<<<dim3(HW / 128, 1), 256, 0, stream>>>(hb, wT1, b1, y1, Cc);
        reduce_stats<<<NB_RED, 256, 0, stream>>>(y1, part);
        finalize_stats<<<1, 256, 0, stream>>>(part, stats + 2 * b);
        norm_silu<<<(Cc * HW) / 256, 256, 0, stream>>>(y1, g, lb, stats + 2 * b);
        conv_gemm<<<dim3(HW / 128, 2), 256, 0, stream>>>(y1, wT2, b2, vel, 2 * Cc);
        pix_trig<<<(HW + 255) / 256, 256, 0, stream>>>(latg + (size_t)b * HW, dbuf);
        semilag<<<(Cc * HW) / 256, 256, 0, stream>>>(vel, hb, dbuf,
                                                     lng + (size_t)b * HW, dt,
                                                     out + (size_t)b * Cc * HW);
    }
}

// Round 6
// 4635.073 us; speedup vs baseline: 1.3213x; 1.3213x over previous
//
#include <hip/hip_runtime.h>
#include <math.h>

#define Hh 240
#define Ww 480
#define HW 115200      // Hh*Ww
#define Cc 128
#define Kk 1152        // Cc*9
#define HALFW 240      // Ww/2
#define NB_RED 1440

typedef unsigned int u32;
typedef __attribute__((address_space(3))) u32 lds_u32;
typedef const __attribute__((address_space(1))) u32 glb_u32;

// ---------------------------------------------------------------------------
// geo_pad-fused index: flat index into a [C][H][W] plane for padded coords
// (r in [-1,Hh], c in [-1,Ww]).
// ---------------------------------------------------------------------------
__device__ __forceinline__ int geo_index(int ch, int r, int c) {
    int wv = (c < 0) ? (Ww - 1) : ((c >= Ww) ? 0 : c);
    int rr;
    if (r < 0)        { rr = 0;      wv = (wv >= HALFW) ? wv - HALFW : wv + HALFW; }
    else if (r >= Hh) { rr = Hh - 1; wv = (wv >= HALFW) ? wv - HALFW : wv + HALFW; }
    else              { rr = r; }
    return (ch * Hh + rr) * Ww + wv;
}

__device__ __forceinline__ float padfetch(const float* __restrict__ p, int yi, int xj) {
    int r = yi - 1, c = xj - 1;
    int wv = (c < 0) ? (Ww - 1) : ((c >= Ww) ? 0 : c);
    int rr;
    if (r < 0)        { rr = 0;      wv = (wv >= HALFW) ? wv - HALFW : wv + HALFW; }
    else if (r >= Hh) { rr = Hh - 1; wv = (wv >= HALFW) ? wv - HALFW : wv + HALFW; }
    else              { rr = r; }
    return p[rr * Ww + wv];
}

// small-angle double sincos (|x| <~ 0.7), libm fallback — IDENTICAL to round 2
__device__ __forceinline__ void sincos_small(double x, double* s, double* c) {
    double x2 = x * x;
    if (x2 > 0.49) { *s = sin(x); *c = cos(x); return; }
    *s = x * (1.0 + x2 * (-1.6666666666666666e-1 + x2 * (8.3333333333333333e-3 +
         x2 * (-1.9841269841269841e-4 + x2 * (2.7557319223985893e-6 - x2 * 2.5052108385441720e-8)))));
    *c = 1.0 + x2 * (-0.5 + x2 * (4.1666666666666666e-2 + x2 * (-1.3888888888888889e-3 +
         x2 * (2.4801587301587302e-5 - x2 * 2.7557319223985893e-7))));
}

// ---------------------------------------------------------------------------
__global__ void transpose_w(const float* __restrict__ w, float* __restrict__ wT, int N) {
    int idx = blockIdx.x * 256 + threadIdx.x;      // idx = k*N + n
    if (idx >= N * Kk) return;
    int k = idx / N;
    int n = idx - k * N;
    wT[idx] = w[n * Kk + k];
}

// ---------------------------------------------------------------------------
// conv2: implicit-GEMM, tile 128(M) x 256(N), BK=16, 256 threads, micro 8x16.
// A and B staged via global_load_lds, double-buffered. Per-output k-order
// identical to prior rounds (ascending k) -> bit-exact.
// ---------------------------------------------------------------------------
__global__ __launch_bounds__(256)
void conv2_gemm(const float* __restrict__ in,    // [Cc][HW] batch plane base
                const float* __restrict__ wT,    // [Kk][256]
                const float* __restrict__ bias,  // [256]
                float* __restrict__ out)         // [256][HW]
{
    const int tid = threadIdx.x;
    const int tx = tid & 15;     // m group (16 threads x 8 outputs)
    const int ty = tid >> 4;     // n group (16 threads x 16 outputs)
    const int m0 = blockIdx.x * 128;

    __shared__ float As[2][16][128];
    __shared__ float Bs[2][16][256];

    // A staging: col = tid&127, rows ki0 + 2i (8 loads)
    const int ki0     = tid >> 7;
    const int colbase = tid & 64;            // wave-uniform
    const int m       = m0 + (tid & 127);
    const int h       = m / Ww;
    const int w       = m - h * Ww;
    // B staging: col = tid (256 cols), rows 0..15 (16 loads)
    const int wbase   = tid & 192;           // wave-uniform 64-col base

    float acc[8][16] = {};

    auto stageA = [&](int buf, int kt) {
        #pragma unroll
        for (int i = 0; i < 8; i++) {
            int k  = kt + ki0 + 2 * i;
            int ic = k / 9;
            int t9 = k - ic * 9;
            int kh = t9 / 3;
            int kw = t9 - kh * 3;
            int gidx = geo_index(ic, h + kh - 1, w + kw - 1);
            __builtin_amdgcn_global_load_lds(
                (glb_u32*)(in + gidx),
                (lds_u32*)&As[buf][ki0 + 2 * i][colbase],
                4, 0, 0);
        }
    };
    auto stageB = [&](int buf, int kt) {
        const float* src = wT + (size_t)kt * 256 + tid;
        #pragma unroll
        for (int i = 0; i < 16; i++) {
            __builtin_amdgcn_global_load_lds(
                (glb_u32*)(src + (size_t)i * 256),
                (lds_u32*)&Bs[buf][i][wbase],
                4, 0, 0);
        }
    };

    stageA(0, 0);
    stageB(0, 0);
    __syncthreads();

    int buf = 0;
    for (int kt = 0; kt < Kk; kt += 16) {
        if (kt + 16 < Kk) { stageA(buf ^ 1, kt + 16); stageB(buf ^ 1, kt + 16); }
        #pragma unroll
        for (int kk = 0; kk < 16; kk++) {
            float4 a0 = *(const float4*)&As[buf][kk][tx * 4];
            float4 a1 = *(const float4*)&As[buf][kk][64 + tx * 4];
            float4 b0 = *(const float4*)&Bs[buf][kk][ty * 4];
            float4 b1 = *(const float4*)&Bs[buf][kk][64 + ty * 4];
            float4 b2 = *(const float4*)&Bs[buf][kk][128 + ty * 4];
            float4 b3 = *(const float4*)&Bs[buf][kk][192 + ty * 4];
            float av[8]  = {a0.x, a0.y, a0.z, a0.w, a1.x, a1.y, a1.z, a1.w};
            float bv[16] = {b0.x, b0.y, b0.z, b0.w, b1.x, b1.y, b1.z, b1.w,
                            b2.x, b2.y, b2.z, b2.w, b3.x, b3.y, b3.z, b3.w};
            #pragma unroll
            for (int i = 0; i < 8; i++)
                #pragma unroll
                for (int j = 0; j < 16; j++)
                    acc[i][j] = fmaf(av[i], bv[j], acc[i][j]);
        }
        __syncthreads();
        buf ^= 1;
    }

    #pragma unroll
    for (int hn = 0; hn < 4; hn++)
        #pragma unroll
        for (int j = 0; j < 4; j++) {
            int n = hn * 64 + ty * 4 + j;
            float bv = bias[n];
            #pragma unroll
            for (int hm = 0; hm < 2; hm++) {
                float4 o;
                o.x = acc[hm * 4 + 0][hn * 4 + j] + bv;
                o.y = acc[hm * 4 + 1][hn * 4 + j] + bv;
                o.z = acc[hm * 4 + 2][hn * 4 + j] + bv;
                o.w = acc[hm * 4 + 3][hn * 4 + j] + bv;
                *(float4*)&out[(size_t)n * HW + m0 + hm * 64 + tx * 4] = o;
            }
        }
}

// ---------------------------------------------------------------------------
// conv1: implicit-GEMM, tile 256(M) x 128(N), BK=16, 256 threads, micro 16x8.
// ---------------------------------------------------------------------------
__global__ __launch_bounds__(256)
void conv1_gemm(const float* __restrict__ in,    // [Cc][HW] batch plane base
                const float* __restrict__ wT,    // [Kk][128]
                const float* __restrict__ bias,  // [128]
                float* __restrict__ out)         // [128][HW]
{
    const int tid = threadIdx.x;
    const int tx = tid & 15;     // m group (16 threads x 16 outputs)
    const int ty = tid >> 4;     // n group (16 threads x 8 outputs)
    const int m0 = blockIdx.x * 256;

    __shared__ float As[2][16][256];
    __shared__ float Bs[2][16][128];

    // A staging: col = tid (256 cols), rows 0..15 (16 loads)
    const int wbase = tid & 192;             // wave-uniform
    const int m     = m0 + tid;
    const int h     = m / Ww;
    const int w     = m - h * Ww;
    // B staging: col = tid&127, rows ki0 + 2i (8 loads)
    const int ki0     = tid >> 7;
    const int colbase = tid & 64;

    float acc[16][8] = {};

    auto stageA = [&](int buf, int kt) {
        #pragma unroll
        for (int i = 0; i < 16; i++) {
            int k  = kt + i;
            int ic = k / 9;
            int t9 = k - ic * 9;
            int kh = t9 / 3;
            int kw = t9 - kh * 3;
            int gidx = geo_index(ic, h + kh - 1, w + kw - 1);
            __builtin_amdgcn_global_load_lds(
                (glb_u32*)(in + gidx),
                (lds_u32*)&As[buf][i][wbase],
                4, 0, 0);
        }
    };
    auto stageB = [&](int buf, int kt) {
        const float* src = wT + (size_t)(kt + ki0) * 128 + (tid & 127);
        #pragma unroll
        for (int i = 0; i < 8; i++) {
            __builtin_amdgcn_global_load_lds(
                (glb_u32*)(src + (size_t)(2 * i) * 128),
                (lds_u32*)&Bs[buf][ki0 + 2 * i][colbase],
                4, 0, 0);
        }
    };

    stageA(0, 0);
    stageB(0, 0);
    __syncthreads();

    int buf = 0;
    for (int kt = 0; kt < Kk; kt += 16) {
        if (kt + 16 < Kk) { stageA(buf ^ 1, kt + 16); stageB(buf ^ 1, kt + 16); }
        #pragma unroll
        for (int kk = 0; kk < 16; kk++) {
            float4 a0 = *(const float4*)&As[buf][kk][tx * 4];
            float4 a1 = *(const float4*)&As[buf][kk][64 + tx * 4];
            float4 a2 = *(const float4*)&As[buf][kk][128 + tx * 4];
            float4 a3 = *(const float4*)&As[buf][kk][192 + tx * 4];
            float4 b0 = *(const float4*)&Bs[buf][kk][ty * 4];
            float4 b1 = *(const float4*)&Bs[buf][kk][64 + ty * 4];
            float av[16] = {a0.x, a0.y, a0.z, a0.w, a1.x, a1.y, a1.z, a1.w,
                            a2.x, a2.y, a2.z, a2.w, a3.x, a3.y, a3.z, a3.w};
            float bv[8]  = {b0.x, b0.y, b0.z, b0.w, b1.x, b1.y, b1.z, b1.w};
            #pragma unroll
            for (int i = 0; i < 16; i++)
                #pragma unroll
                for (int j = 0; j < 8; j++)
                    acc[i][j] = fmaf(av[i], bv[j], acc[i][j]);
        }
        __syncthreads();
        buf ^= 1;
    }

    #pragma unroll
    for (int hn = 0; hn < 2; hn++)
        #pragma unroll
        for (int j = 0; j < 4; j++) {
            int n = hn * 64 + ty * 4 + j;
            float bv = bias[n];
            #pragma unroll
            for (int q = 0; q < 4; q++) {
                float4 o;
                o.x = acc[q * 4 + 0][hn * 4 + j] + bv;
                o.y = acc[q * 4 + 1][hn * 4 + j] + bv;
                o.z = acc[q * 4 + 2][hn * 4 + j] + bv;
                o.w = acc[q * 4 + 3][hn * 4 + j] + bv;
                *(float4*)&out[(size_t)n * HW + m0 + q * 64 + tx * 4] = o;
            }
        }
}

// ---------------------------------------------------------------------------
// deterministic two-stage LayerNorm stats
// ---------------------------------------------------------------------------
__global__ __launch_bounds__(256)
void reduce_stats(const float* __restrict__ y, float* __restrict__ part) {
    const int n4 = (Cc * HW) / 4;
    float s = 0.f, ss = 0.f;
    for (int i = blockIdx.x * 256 + threadIdx.x; i < n4; i += NB_RED * 256) {
        float4 v = ((const float4*)y)[i];
        s  += v.x + v.y + v.z + v.w;
        ss += v.x * v.x + v.y * v.y + v.z * v.z + v.w * v.w;
    }
    #pragma unroll
    for (int o = 32; o > 0; o >>= 1) { s += __shfl_down(s, o); ss += __shfl_down(ss, o); }
    __shared__ float ls[4], lss[4];
    int wid = threadIdx.x >> 6, lane = threadIdx.x & 63;
    if (lane == 0) { ls[wid] = s; lss[wid] = ss; }
    __syncthreads();
    if (threadIdx.x == 0) {
        part[blockIdx.x * 2]     = ls[0] + ls[1] + ls[2] + ls[3];
        part[blockIdx.x * 2 + 1] = lss[0] + lss[1] + lss[2] + lss[3];
    }
}

__global__ __launch_bounds__(256)
void finalize_stats(const float* __restrict__ part, float* __restrict__ stats) {
    float s = 0.f, ss = 0.f;
    for (int i = threadIdx.x; i < NB_RED; i += 256) { s += part[2 * i]; ss += part[2 * i + 1]; }
    #pragma unroll
    for (int o = 32; o > 0; o >>= 1) { s += __shfl_down(s, o); ss += __shfl_down(ss, o); }
    __shared__ float ls[4], lss[4];
    int wid = threadIdx.x >> 6, lane = threadIdx.x & 63;
    if (lane == 0) { ls[wid] = s; lss[wid] = ss; }
    __syncthreads();
    if (threadIdx.x == 0) {
        stats[0] = ls[0] + ls[1] + ls[2] + ls[3];
        stats[1] = lss[0] + lss[1] + lss[2] + lss[3];
    }
}

__global__ void norm_silu(float* __restrict__ y, const float* __restrict__ g,
                          const float* __restrict__ bb, const float* __restrict__ stats) {
    int i = blockIdx.x * 256 + threadIdx.x;
    if (i >= Cc * HW) return;
    const float invN = 1.f / (float)(Cc * HW);
    float mu  = stats[0] * invN;
    float var = stats[1] * invN - mu * mu;
    float inv = rsqrtf(var + 1e-5f);
    float z = (y[i] - mu) * inv * g[i] + bb[i];
    y[i] = z / (1.f + expf(-z));
}

// ---------------------------------------------------------------------------
__global__ void pix_trig(const float* __restrict__ latg, double* __restrict__ sphid) {
    int m = blockIdx.x * 256 + threadIdx.x;
    if (m >= HW) return;
    double phi = (double)latg[m];
    sphid[m]      = sin(phi);
    sphid[HW + m] = cos(phi);
}

// ---------------------------------------------------------------------------
// departure-point trig + bicubic sample. Hybrid precision: fp32 fast path for
// low-amplification pixels; bit-identical-to-round-2 fp64 path otherwise.
// ---------------------------------------------------------------------------
__global__ __launch_bounds__(256)
void semilag(const float* __restrict__ vel,     // [2*Cc][HW] batch base
             const float* __restrict__ hid,     // [Cc][HW] batch base
             const double* __restrict__ sphid,  // [2][HW] sin/cos(lat)
             const float* __restrict__ lng,     // [HW]
             const float* __restrict__ dtp,
             float* __restrict__ out)           // [Cc][HW] batch base
{
    int idx = blockIdx.x * 256 + threadIdx.x;
    if (idx >= Cc * HW) return;
    int c = idx / HW;
    int m = idx - c * HW;

    const double TWO_PI = 6.2831853071795864769252867665590;
    const double PI_D   = 3.1415926535897932384626433832795;
    const float  PI2F   = 6.28318530717958647692f;

    float uf = vel[idx];
    float vf = vel[Cc * HW + idx];
    float dtf = dtp[0];
    double sphi_d = sphid[m], cphi_d = sphid[HW + m];
    float lam_f = lng[m];

    // ---- fp32 gate evaluation ----
    float lonp_f = -uf * dtf, latp_f = -vf * dtf;
    float slp_f = sinf(latp_f), clp_f = cosf(latp_f);
    float slo_f = sinf(lonp_f), clo_f = cosf(lonp_f);
    float sphi_f = (float)sphi_d, cphi_f = (float)cphi_d;
    float sinlat_f = slp_f * cphi_f + clp_f * clo_f * sphi_f;
    float num_f = clp_f * slo_f;
    float den_f = clp_f * clo_f * cphi_f - slp_f * sphi_f;
    float r2_f  = num_f * num_f + den_f * den_f;

    float lon_w = lam_f + atan2f(num_f, den_f) + PI2F;
    lon_w = lon_w - floorf(lon_w / PI2F) * PI2F;
    float seam = fminf(lon_w, PI2F - lon_w);

    bool fast = (cphi_f > 0.2f) & (r2_f > 0.01f) & (fabsf(sinlat_f) < 0.98f) & (seam > 1e-4f);

    double ixd, iyd;
    if (fast) {
        float sl = fminf(fmaxf(sinlat_f, -1.f + 1e-7f), 1.f - 1e-7f);
        float lat_dep = asinf(sl);
        float gx = (lon_w / PI2F * 2.f - 1.f) * (480.f / 482.f);
        float gy = (lat_dep / 3.14159265358979323846f * 2.f - 1.f) * (240.f / 242.f);
        ixd = (double)fminf(fmaxf((gx + 1.f) * 0.5f * 481.f, 0.f), 481.f);
        iyd = (double)fminf(fmaxf((gy + 1.f) * 0.5f * 241.f, 0.f), 241.f);
    } else {
        // ---- fp64 path: IDENTICAL arithmetic to round 2 ----
        double dt = (double)dtf;
        double u = (double)uf;
        double v = (double)vf;
        double lonp = -u * dt, latp = -v * dt;
        double slp, clp, slo, clo;
        sincos_small(latp, &slp, &clp);
        sincos_small(lonp, &slo, &clo);
        double sphi = sphi_d, cphi = cphi_d;

        double sinlat = slp * cphi + clp * clo * sphi;
        sinlat = fmin(fmax(sinlat, -1.0 + 1e-7), 1.0 - 1e-7);
        double lat_dep = asin(sinlat);

        double num = clp * slo;
        double den = clp * clo * cphi - slp * sphi;
        double lon_dep = (double)lam_f + atan2(num, den);
        double xr = lon_dep + TWO_PI;
        xr = xr - floor(xr / TWO_PI) * TWO_PI;

        double gx = (xr / TWO_PI * 2.0 - 1.0) * (480.0 / 482.0);
        double gy = (lat_dep / PI_D * 2.0 - 1.0) * (240.0 / 242.0);

        ixd = fmin(fmax((gx + 1.0) * 0.5 * 481.0, 0.0), 481.0);
        iyd = fmin(fmax((gy + 1.0) * 0.5 * 241.0, 0.0), 241.0);
    }

    double x0d = floor(ixd), y0d = floor(iyd);
    float fx = (float)(ixd - x0d), fy = (float)(iyd - y0d);
    int x0 = (int)x0d, y0 = (int)y0d;

    const float a = -0.75f;
    float wx[4], wy[4];
    {
        float t = fx;
        float t1 = 1.f + t, t2 = 2.f - t, s1 = 1.f - t;
        wx[0] = ((a * t1 - 5.f * a) * t1 + 8.f * a) * t1 - 4.f * a;
        wx[1] = ((a + 2.f) * t - (a + 3.f)) * t * t + 1.f;
        wx[2] = ((a + 2.f) * s1 - (a + 3.f)) * s1 * s1 + 1.f;
        wx[3] = ((a * t2 - 5.f * a) * t2 + 8.f * a) * t2 - 4.f * a;
        t = fy;
        t1 = 1.f + t; t2 = 2.f - t; s1 = 1.f - t;
        wy[0] = ((a * t1 - 5.f * a) * t1 + 8.f * a) * t1 - 4.f * a;
        wy[1] = ((a + 2.f) * t - (a + 3.f)) * t * t + 1.f;
        wy[2] = ((a + 2.f) * s1 - (a + 3.f)) * s1 * s1 + 1.f;
        wy[3] = ((a * t2 - 5.f * a) * t2 + 8.f * a) * t2 - 4.f * a;
    }

    const float* plane = hid + (size_t)c * HW;
    float accv = 0.f;
    #pragma unroll
    for (int i = 0; i < 4; i++) {
        int yi = min(max(y0 + i - 1, 0), 241);
        float row = 0.f;
        #pragma unroll
        for (int j = 0; j < 4; j++) {
            int xj = min(max(x0 + j - 1, 0), 481);
            row = fmaf(wx[j], padfetch(plane, yi, xj), row);
        }
        accv = fmaf(wy[i], row, accv);
    }
    out[idx] = accv;
}

// ---------------------------------------------------------------------------
extern "C" void kernel_launch(void* const* d_in, const int* in_sizes, int n_in,
                              void* d_out, int out_size, void* d_ws, size_t ws_size,
                              hipStream_t stream)
{
    const float* hidden = (const float*)d_in[0];
    const float* latg   = (const float*)d_in[1];
    const float* lng    = (const float*)d_in[2];
    const float* w1     = (const float*)d_in[3];
    const float* b1     = (const float*)d_in[4];
    const float* g      = (const float*)d_in[5];
    const float* lb     = (const float*)d_in[6];
    const float* w2     = (const float*)d_in[7];
    const float* b2     = (const float*)d_in[8];
    const float* dt     = (const float*)d_in[9];
    float* out = (float*)d_out;

    // ws layout (floats): stats[4] | part[2880] | wT1 | wT2 | y1[C*HW] | vel[2C*HW]
    float* ws    = (float*)d_ws;
    float* stats = ws;
    float* part  = ws + 4;
    float* wT1   = part + 2 * NB_RED;
    float* wT2   = wT1 + Kk * Cc;
    float* y1    = wT2 + Kk * 2 * Cc;
    float* vel   = y1 + (size_t)Cc * HW;
    double* dbuf = (double*)y1;   // y1 region reused after conv2 (8B-aligned)

    transpose_w<<<(Cc * Kk + 255) / 256, 256, 0, stream>>>(w1, wT1, Cc);
    transpose_w<<<(2 * Cc * Kk + 255) / 256, 256, 0, stream>>>(w2, wT2, 2 * Cc);

    for (int b = 0; b < 2; b++) {
        const float* hb = hidden + (size_t)b * Cc * HW;
        conv1_gemm<<<dim3(HW / 256), 256, 0, stream>>>(hb, wT1, b1, y1);
        reduce_stats<<<NB_RED, 256, 0, stream>>>(y1, part);
        finalize_stats<<<1, 256, 0, stream>>>(part, stats + 2 * b);
        norm_silu<<<(Cc * HW) / 256, 256, 0, stream>>>(y1, g, lb, stats + 2 * b);
        conv2_gemm<<<dim3(HW / 128), 256, 0, stream>>>(y1, wT2, b2, vel);
        pix_trig<<<(HW + 255) / 256, 256, 0, stream>>>(latg + (size_t)b * HW, dbuf);
        semilag<<<(Cc * HW) / 256, 256, 0, stream>>>(vel, hb, dbuf,
                                                     lng + (size_t)b * HW, dt,
                                                     out + (size_t)b * Cc * HW);
    }
}

// Round 7
// 3920.373 us; speedup vs baseline: 1.5621x; 1.1823x over previous
//
#include <hip/hip_runtime.h>
#include <math.h>

#define Hh 240
#define Ww 480
#define HW 115200      // Hh*Ww
#define Cc 128
#define Kk 1152        // Cc*9
#define HALFW 240      // Ww/2
#define NB_RED 1440
#define WLCAP 4194304

typedef unsigned int u32;
typedef unsigned short u16;
typedef short bf16x8 __attribute__((ext_vector_type(8)));   // 8 bf16 = 4 VGPR
typedef float f32x4 __attribute__((ext_vector_type(4)));

// ---------------------------------------------------------------------------
// bf16 split helpers: x == bf2f(x1)+bf2f(x2)+bf2f(x3) EXACTLY (3x8=24 bits)
// ---------------------------------------------------------------------------
__device__ __forceinline__ u16 f2bf(float x) {
    u32 u = __float_as_uint(x);
    u32 r = (u + 0x7fffu + ((u >> 16) & 1u)) >> 16;
    return (u16)r;
}
__device__ __forceinline__ float bf2f(u16 h) { return __uint_as_float(((u32)h) << 16); }

// geo_pad spatial index (channel-independent part)
__device__ __forceinline__ int geo_sidx(int r, int c) {
    int wv = (c < 0) ? (Ww - 1) : ((c >= Ww) ? 0 : c);
    int rr;
    if (r < 0)        { rr = 0;      wv = (wv >= HALFW) ? wv - HALFW : wv + HALFW; }
    else if (r >= Hh) { rr = Hh - 1; wv = (wv >= HALFW) ? wv - HALFW : wv + HALFW; }
    else              { rr = r; }
    return rr * Ww + wv;
}

__device__ __forceinline__ float padfetch(const float* __restrict__ p, int yi, int xj) {
    return p[geo_sidx(yi - 1, xj - 1)];
}

// small-angle double sincos (|x| <~ 0.7), libm fallback — IDENTICAL to round 2
__device__ __forceinline__ void sincos_small(double x, double* s, double* c) {
    double x2 = x * x;
    if (x2 > 0.49) { *s = sin(x); *c = cos(x); return; }
    *s = x * (1.0 + x2 * (-1.6666666666666666e-1 + x2 * (8.3333333333333333e-3 +
         x2 * (-1.9841269841269841e-4 + x2 * (2.7557319223985893e-6 - x2 * 2.5052108385441720e-8)))));
    *c = 1.0 + x2 * (-0.5 + x2 * (4.1666666666666666e-2 + x2 * (-1.3888888888888889e-3 +
         x2 * (2.4801587301587302e-5 - x2 * 2.7557319223985893e-7))));
}

// ---------------------------------------------------------------------------
// split weights [N][Kk] fp32 -> 3 bf16 planes [p][N][Kk]
// ---------------------------------------------------------------------------
__global__ void split_w(const float* __restrict__ w, u16* __restrict__ sp, int total) {
    int i = blockIdx.x * 256 + threadIdx.x;
    if (i >= total) return;
    float x = w[i];
    u16 a = f2bf(x); float r1 = x - bf2f(a);
    u16 b = f2bf(r1); float r2 = r1 - bf2f(b);
    sp[i] = a; sp[total + i] = b; sp[2 * total + i] = f2bf(r2);
}

// ---------------------------------------------------------------------------
// MFMA implicit-GEMM conv (bf16x3, 6-pass). Tile 128(M) x NN(N), K-step 32.
// 4 waves (2M x 2N). mfma_f32_16x16x32_bf16. A split on the fly from fp32
// (geo_pad-fused gather); B from pre-split planes.
// ---------------------------------------------------------------------------
template<int NN>
__global__ __launch_bounds__(256)
void conv_mfma(const float* __restrict__ in,     // [Cc][HW] batch plane
               const u16*  __restrict__ wsp,     // [3][NN][Kk] bf16 planes
               const float* __restrict__ bias,   // [NN]
               float* __restrict__ out)          // [NN][HW]
{
    constexpr int NT = NN / 32;                  // n-tiles per wave
    __shared__ short Al[3][128][40];             // [plane][m][k] rows padded to 80B
    __shared__ short Bl[3][NN][40];              // [plane][n][k]

    const int tid  = threadIdx.x;
    const int lane = tid & 63;
    const int wave = tid >> 6;
    const int wm = wave & 1, wn = wave >> 1;
    const int lr = lane & 15, kg = lane >> 4;
    const int m0 = blockIdx.x * 128;

    // A staging identity: thread stages m = tid&127, k-range (tid>>7)*16..+16
    const int ms = tid & 127;
    const int ks = (tid >> 7) * 16;
    const int gm = m0 + ms;
    const int h = gm / Ww, w = gm - h * Ww;
    int sidx[9];
    #pragma unroll
    for (int q = 0; q < 9; q++) sidx[q] = geo_sidx(h + q / 3 - 1, w + q % 3 - 1);

    f32x4 acc[4][NT] = {};

    for (int kt = 0; kt < Kk; kt += 32) {
        __syncthreads();
        // ---- stage A: fp32 gather -> bf16x3 split -> LDS ----
        {
            int k = kt + ks;
            int ic = k / 9, t9 = k - ic * 9;
            short hh[3][16];
            #pragma unroll
            for (int j = 0; j < 16; j++) {
                float x = in[ic * HW + sidx[t9]];
                u16 a = f2bf(x); float r1 = x - bf2f(a);
                u16 b = f2bf(r1); float r2 = r1 - bf2f(b);
                hh[0][j] = (short)a; hh[1][j] = (short)b; hh[2][j] = (short)f2bf(r2);
                if (++t9 == 9) { t9 = 0; ic++; }
            }
            #pragma unroll
            for (int p = 0; p < 3; p++) {
                bf16x8 v0, v1;
                #pragma unroll
                for (int j = 0; j < 8; j++) { v0[j] = hh[p][j]; v1[j] = hh[p][8 + j]; }
                *(bf16x8*)&Al[p][ms][ks]     = v0;
                *(bf16x8*)&Al[p][ms][ks + 8] = v1;
            }
        }
        // ---- stage B: pre-split planes, coalesced 16B chunks ----
        {
            constexpr int NCH = 3 * NN * 4 / 256;
            #pragma unroll
            for (int cg = 0; cg < NCH; cg++) {
                int chunk = tid + cg * 256;
                int p = chunk / (NN * 4);
                int rem = chunk - p * NN * 4;
                int n = rem >> 2, part = rem & 3;
                bf16x8 v = *(const bf16x8*)&wsp[(size_t)(p * NN + n) * Kk + kt + part * 8];
                *(bf16x8*)&Bl[p][n][part * 8] = v;
            }
        }
        __syncthreads();
        // ---- 6 passes grouped by B plane: (pa,pb) with pa+pb<=2 ----
        #pragma unroll
        for (int pb = 0; pb < 3; pb++) {
            bf16x8 bq[NT];
            #pragma unroll
            for (int nt = 0; nt < NT; nt++)
                bq[nt] = *(const bf16x8*)&Bl[pb][wn * (NN / 2) + nt * 16 + lr][kg * 8];
            #pragma unroll
            for (int pa = 0; pa < 3 - pb; pa++) {
                #pragma unroll
                for (int mt = 0; mt < 4; mt++) {
                    bf16x8 af = *(const bf16x8*)&Al[pa][wm * 64 + mt * 16 + lr][kg * 8];
                    #pragma unroll
                    for (int nt = 0; nt < NT; nt++)
                        acc[mt][nt] = __builtin_amdgcn_mfma_f32_16x16x32_bf16(
                            af, bq[nt], acc[mt][nt], 0, 0, 0);
                }
            }
        }
    }
    // epilogue: D col = lane&15 (n), rows = kg*4+reg (m)
    #pragma unroll
    for (int mt = 0; mt < 4; mt++) {
        int mbase = m0 + wm * 64 + mt * 16 + kg * 4;
        #pragma unroll
        for (int nt = 0; nt < NT; nt++) {
            int n = wn * (NN / 2) + nt * 16 + lr;
            float bv = bias[n];
            float4 o;
            o.x = acc[mt][nt][0] + bv;
            o.y = acc[mt][nt][1] + bv;
            o.z = acc[mt][nt][2] + bv;
            o.w = acc[mt][nt][3] + bv;
            *(float4*)&out[(size_t)n * HW + mbase] = o;
        }
    }
}

// ---------------------------------------------------------------------------
// deterministic two-stage LayerNorm stats (unchanged)
// ---------------------------------------------------------------------------
__global__ __launch_bounds__(256)
void reduce_stats(const float* __restrict__ y, float* __restrict__ part) {
    const int n4 = (Cc * HW) / 4;
    float s = 0.f, ss = 0.f;
    for (int i = blockIdx.x * 256 + threadIdx.x; i < n4; i += NB_RED * 256) {
        float4 v = ((const float4*)y)[i];
        s  += v.x + v.y + v.z + v.w;
        ss += v.x * v.x + v.y * v.y + v.z * v.z + v.w * v.w;
    }
    #pragma unroll
    for (int o = 32; o > 0; o >>= 1) { s += __shfl_down(s, o); ss += __shfl_down(ss, o); }
    __shared__ float ls[4], lss[4];
    int wid = threadIdx.x >> 6, lane = threadIdx.x & 63;
    if (lane == 0) { ls[wid] = s; lss[wid] = ss; }
    __syncthreads();
    if (threadIdx.x == 0) {
        part[blockIdx.x * 2]     = ls[0] + ls[1] + ls[2] + ls[3];
        part[blockIdx.x * 2 + 1] = lss[0] + lss[1] + lss[2] + lss[3];
    }
}

__global__ __launch_bounds__(256)
void finalize_stats(const float* __restrict__ part, float* __restrict__ stats) {
    float s = 0.f, ss = 0.f;
    for (int i = threadIdx.x; i < NB_RED; i += 256) { s += part[2 * i]; ss += part[2 * i + 1]; }
    #pragma unroll
    for (int o = 32; o > 0; o >>= 1) { s += __shfl_down(s, o); ss += __shfl_down(ss, o); }
    __shared__ float ls[4], lss[4];
    int wid = threadIdx.x >> 6, lane = threadIdx.x & 63;
    if (lane == 0) { ls[wid] = s; lss[wid] = ss; }
    __syncthreads();
    if (threadIdx.x == 0) {
        stats[0] = ls[0] + ls[1] + ls[2] + ls[3];
        stats[1] = lss[0] + lss[1] + lss[2] + lss[3];
    }
}

__global__ void norm_silu(float* __restrict__ y, const float* __restrict__ g,
                          const float* __restrict__ bb, const float* __restrict__ stats) {
    int i = blockIdx.x * 256 + threadIdx.x;
    if (i >= Cc * HW) return;
    const float invN = 1.f / (float)(Cc * HW);
    float mu  = stats[0] * invN;
    float var = stats[1] * invN - mu * mu;
    float inv = rsqrtf(var + 1e-5f);
    float z = (y[i] - mu) * inv * g[i] + bb[i];
    y[i] = z / (1.f + expf(-z));
}

// ---------------------------------------------------------------------------
// semilag fast path (pure fp32) + worklist of high-amplification pixels
// ---------------------------------------------------------------------------
__global__ __launch_bounds__(256)
void semilag(const float* __restrict__ vel, const float* __restrict__ hid,
             const float* __restrict__ latg, const float* __restrict__ lng,
             const float* __restrict__ dtp, float* __restrict__ out,
             u32* __restrict__ wl, u32* __restrict__ wlcnt)
{
    int idx = blockIdx.x * 256 + threadIdx.x;
    if (idx >= Cc * HW) return;
    int c = idx / HW;
    int m = idx - c * HW;

    const float PI2F = 6.28318530717958647692f;

    float uf = vel[idx];
    float vf = vel[Cc * HW + idx];
    float dtf = dtp[0];
    float phi = latg[m], lam = lng[m];
    float sphi = sinf(phi), cphi = cosf(phi);

    float lonp = -uf * dtf, latp = -vf * dtf;
    float slp = sinf(latp), clp = cosf(latp);
    float slo = sinf(lonp), clo = cosf(lonp);
    float sinlat = slp * cphi + clp * clo * sphi;
    float num = clp * slo;
    float den = clp * clo * cphi - slp * sphi;
    float r2 = num * num + den * den;

    float lon_w = lam + atan2f(num, den) + PI2F;
    lon_w = lon_w - floorf(lon_w / PI2F) * PI2F;
    float seam = fminf(lon_w, PI2F - lon_w);

    bool snipe = (cphi < 0.02f) || (r2 < 1e-4f) ||
                 (fabsf(sinlat) > 1.f - 1e-5f) || (seam < 1e-3f);
    if (snipe) {
        u32 s = atomicAdd(wlcnt, 1u);
        if (s < WLCAP) wl[s] = (u32)idx;
    }

    float sl = fminf(fmaxf(sinlat, -1.f + 1e-7f), 1.f - 1e-7f);
    float lat_dep = asinf(sl);
    float gx = (lon_w / PI2F * 2.f - 1.f) * (480.f / 482.f);
    float gy = (lat_dep / 3.14159265358979323846f * 2.f - 1.f) * (240.f / 242.f);
    double ixd = (double)fminf(fmaxf((gx + 1.f) * 0.5f * 481.f, 0.f), 481.f);
    double iyd = (double)fminf(fmaxf((gy + 1.f) * 0.5f * 241.f, 0.f), 241.f);

    double x0d = floor(ixd), y0d = floor(iyd);
    float fx = (float)(ixd - x0d), fy = (float)(iyd - y0d);
    int x0 = (int)x0d, y0 = (int)y0d;

    const float a = -0.75f;
    float wx[4], wy[4];
    {
        float t = fx;
        float t1 = 1.f + t, t2 = 2.f - t, s1 = 1.f - t;
        wx[0] = ((a * t1 - 5.f * a) * t1 + 8.f * a) * t1 - 4.f * a;
        wx[1] = ((a + 2.f) * t - (a + 3.f)) * t * t + 1.f;
        wx[2] = ((a + 2.f) * s1 - (a + 3.f)) * s1 * s1 + 1.f;
        wx[3] = ((a * t2 - 5.f * a) * t2 + 8.f * a) * t2 - 4.f * a;
        t = fy;
        t1 = 1.f + t; t2 = 2.f - t; s1 = 1.f - t;
        wy[0] = ((a * t1 - 5.f * a) * t1 + 8.f * a) * t1 - 4.f * a;
        wy[1] = ((a + 2.f) * t - (a + 3.f)) * t * t + 1.f;
        wy[2] = ((a + 2.f) * s1 - (a + 3.f)) * s1 * s1 + 1.f;
        wy[3] = ((a * t2 - 5.f * a) * t2 + 8.f * a) * t2 - 4.f * a;
    }

    const float* plane = hid + (size_t)c * HW;
    float accv = 0.f;
    #pragma unroll
    for (int i = 0; i < 4; i++) {
        int yi = min(max(y0 + i - 1, 0), 241);
        float row = 0.f;
        #pragma unroll
        for (int j = 0; j < 4; j++) {
            int xj = min(max(x0 + j - 1, 0), 481);
            row = fmaf(wx[j], padfetch(plane, yi, xj), row);
        }
        accv = fmaf(wy[i], row, accv);
    }
    out[idx] = accv;
}

// ---------------------------------------------------------------------------
// sniper: per worklist entry, recompute u,v as exact fp64 dot (K=1152) over
// post-SiLU y1, then round-2 fp64 trig + bicubic; overwrite out[idx].
// One wave per entry; grid-stride over the worklist.
// ---------------------------------------------------------------------------
__global__ __launch_bounds__(256)
void sniper(const u32* __restrict__ wl, const u32* __restrict__ wlcnt,
            const float* __restrict__ y1, const float* __restrict__ w2,
            const float* __restrict__ b2, const float* __restrict__ hid,
            const float* __restrict__ latg, const float* __restrict__ lng,
            const float* __restrict__ dtp, float* __restrict__ out)
{
    const int lane = threadIdx.x & 63;
    const int wavid = (blockIdx.x * 256 + threadIdx.x) >> 6;
    const int nwaves = gridDim.x * 4;
    int n = (int)*wlcnt; if (n > WLCAP) n = WLCAP;

    const double TWO_PI = 6.2831853071795864769252867665590;
    const double PI_D   = 3.1415926535897932384626433832795;

    for (int e = wavid; e < n; e += nwaves) {
        u32 idx = wl[e];
        int c = idx / HW, m = idx - c * HW;
        int h = m / Ww, w = m - h * Ww;
        int sidx[9];
        #pragma unroll
        for (int q = 0; q < 9; q++) sidx[q] = geo_sidx(h + q / 3 - 1, w + q % 3 - 1);

        double su = 0.0, sv = 0.0;
        #pragma unroll 2
        for (int j = 0; j < 18; j++) {
            int k = j * 64 + lane;
            int ic = k / 9, t9 = k - ic * 9;
            double yv = (double)y1[ic * HW + sidx[t9]];
            su = fma((double)w2[(size_t)c * Kk + k], yv, su);
            sv = fma((double)w2[(size_t)(Cc + c) * Kk + k], yv, sv);
        }
        #pragma unroll
        for (int o = 32; o > 0; o >>= 1) {
            su += __shfl_down(su, o);
            sv += __shfl_down(sv, o);
        }
        if (lane == 0) {
            double u = (double)b2[c] + su;
            double v = (double)b2[Cc + c] + sv;
            double dt = (double)dtp[0];
            double lonp = -u * dt, latp = -v * dt;
            double slp, clp, slo, clo;
            sincos_small(latp, &slp, &clp);
            sincos_small(lonp, &slo, &clo);
            double phi = (double)latg[m];
            double sphi = sin(phi), cphi = cos(phi);

            double sinlat = slp * cphi + clp * clo * sphi;
            sinlat = fmin(fmax(sinlat, -1.0 + 1e-7), 1.0 - 1e-7);
            double lat_dep = asin(sinlat);

            double num = clp * slo;
            double den = clp * clo * cphi - slp * sphi;
            double lon_dep = (double)lng[m] + atan2(num, den);
            double xr = lon_dep + TWO_PI;
            xr = xr - floor(xr / TWO_PI) * TWO_PI;

            double gx = (xr / TWO_PI * 2.0 - 1.0) * (480.0 / 482.0);
            double gy = (lat_dep / PI_D * 2.0 - 1.0) * (240.0 / 242.0);
            double ixd = fmin(fmax((gx + 1.0) * 0.5 * 481.0, 0.0), 481.0);
            double iyd = fmin(fmax((gy + 1.0) * 0.5 * 241.0, 0.0), 241.0);

            double x0d = floor(ixd), y0d = floor(iyd);
            float fx = (float)(ixd - x0d), fy = (float)(iyd - y0d);
            int x0 = (int)x0d, y0 = (int)y0d;

            const float a = -0.75f;
            float wx[4], wy[4];
            {
                float t = fx;
                float t1 = 1.f + t, t2 = 2.f - t, s1 = 1.f - t;
                wx[0] = ((a * t1 - 5.f * a) * t1 + 8.f * a) * t1 - 4.f * a;
                wx[1] = ((a + 2.f) * t - (a + 3.f)) * t * t + 1.f;
                wx[2] = ((a + 2.f) * s1 - (a + 3.f)) * s1 * s1 + 1.f;
                wx[3] = ((a * t2 - 5.f * a) * t2 + 8.f * a) * t2 - 4.f * a;
                t = fy;
                t1 = 1.f + t; t2 = 2.f - t; s1 = 1.f - t;
                wy[0] = ((a * t1 - 5.f * a) * t1 + 8.f * a) * t1 - 4.f * a;
                wy[1] = ((a + 2.f) * t - (a + 3.f)) * t * t + 1.f;
                wy[2] = ((a + 2.f) * s1 - (a + 3.f)) * s1 * s1 + 1.f;
                wy[3] = ((a * t2 - 5.f * a) * t2 + 8.f * a) * t2 - 4.f * a;
            }
            const float* plane = hid + (size_t)c * HW;
            float accv = 0.f;
            #pragma unroll
            for (int i = 0; i < 4; i++) {
                int yi = min(max(y0 + i - 1, 0), 241);
                float row = 0.f;
                #pragma unroll
                for (int j = 0; j < 4; j++) {
                    int xj = min(max(x0 + j - 1, 0), 481);
                    row = fmaf(wx[j], padfetch(plane, yi, xj), row);
                }
                accv = fmaf(wy[i], row, accv);
            }
            out[idx] = accv;
        }
    }
}

// ---------------------------------------------------------------------------
extern "C" void kernel_launch(void* const* d_in, const int* in_sizes, int n_in,
                              void* d_out, int out_size, void* d_ws, size_t ws_size,
                              hipStream_t stream)
{
    const float* hidden = (const float*)d_in[0];
    const float* latg   = (const float*)d_in[1];
    const float* lng    = (const float*)d_in[2];
    const float* w1     = (const float*)d_in[3];
    const float* b1     = (const float*)d_in[4];
    const float* g      = (const float*)d_in[5];
    const float* lb     = (const float*)d_in[6];
    const float* w2     = (const float*)d_in[7];
    const float* b2     = (const float*)d_in[8];
    const float* dt     = (const float*)d_in[9];
    float* out = (float*)d_out;

    // ws layout: stats[4] part[2880] wlcnt[4B pad to 4 floats]
    //            wsp1[3*128*1152 u16] wsp2[3*256*1152 u16]
    //            y1[C*HW f32] vel[2C*HW f32] wl[WLCAP u32]   (~196 MB)
    float* ws    = (float*)d_ws;
    float* stats = ws;
    float* part  = ws + 4;
    u32*   wlcnt = (u32*)(ws + 4 + 2 * NB_RED);
    u16*   wsp1  = (u16*)(ws + 4 + 2 * NB_RED + 4);
    u16*   wsp2  = wsp1 + (size_t)3 * Cc * Kk;
    float* y1    = (float*)(wsp2 + (size_t)3 * 2 * Cc * Kk);
    float* vel   = y1 + (size_t)Cc * HW;
    u32*   wl    = (u32*)(vel + (size_t)2 * Cc * HW);

    split_w<<<(Cc * Kk + 255) / 256, 256, 0, stream>>>(w1, wsp1, Cc * Kk);
    split_w<<<(2 * Cc * Kk + 255) / 256, 256, 0, stream>>>(w2, wsp2, 2 * Cc * Kk);

    for (int b = 0; b < 2; b++) {
        const float* hb = hidden + (size_t)b * Cc * HW;
        conv_mfma<128><<<HW / 128, 256, 0, stream>>>(hb, wsp1, b1, y1);
        reduce_stats<<<NB_RED, 256, 0, stream>>>(y1, part);
        finalize_stats<<<1, 256, 0, stream>>>(part, stats + 2 * b);
        norm_silu<<<(Cc * HW) / 256, 256, 0, stream>>>(y1, g, lb, stats + 2 * b);
        conv_mfma<256><<<HW / 128, 256, 0, stream>>>(y1, wsp2, b2, vel);
        hipMemsetAsync(wlcnt, 0, 4, stream);
        semilag<<<(Cc * HW) / 256, 256, 0, stream>>>(vel, hb, latg + (size_t)b * HW,
                                                     lng + (size_t)b * HW, dt,
                                                     out + (size_t)b * Cc * HW, wl, wlcnt);
        sniper<<<2048, 256, 0, stream>>>(wl, wlcnt, y1, w2, b2, hb,
                                         latg + (size_t)b * HW, lng + (size_t)b * HW,
                                         dt, out + (size_t)b * Cc * HW);
    }
}

// Round 8
// 3058.930 us; speedup vs baseline: 2.0021x; 1.2816x over previous
//
#include <hip/hip_runtime.h>
#include <math.h>

#define Hh 240
#define Ww 480
#define HW 115200      // Hh*Ww
#define Cc 128
#define Kk 1152        // Cc*9
#define HALFW 240      // Ww/2
#define NB_RED 1440
#define WLCAP 4194304

typedef unsigned int u32;
typedef unsigned short u16;
typedef short bf16x8 __attribute__((ext_vector_type(8)));   // 8 bf16 = 4 VGPR
typedef float f32x4 __attribute__((ext_vector_type(4)));

// ---------------------------------------------------------------------------
// bf16 split helpers: x == bf2f(x1)+bf2f(x2)+bf2f(x3) EXACTLY (3x8=24 bits)
// ---------------------------------------------------------------------------
__device__ __forceinline__ u16 f2bf(float x) {
    u32 u = __float_as_uint(x);
    u32 r = (u + 0x7fffu + ((u >> 16) & 1u)) >> 16;
    return (u16)r;
}
__device__ __forceinline__ float bf2f(u16 h) { return __uint_as_float(((u32)h) << 16); }

// geo_pad spatial index (channel-independent part)
__device__ __forceinline__ int geo_sidx(int r, int c) {
    int wv = (c < 0) ? (Ww - 1) : ((c >= Ww) ? 0 : c);
    int rr;
    if (r < 0)        { rr = 0;      wv = (wv >= HALFW) ? wv - HALFW : wv + HALFW; }
    else if (r >= Hh) { rr = Hh - 1; wv = (wv >= HALFW) ? wv - HALFW : wv + HALFW; }
    else              { rr = r; }
    return rr * Ww + wv;
}

__device__ __forceinline__ float padfetch(const float* __restrict__ p, int yi, int xj) {
    return p[geo_sidx(yi - 1, xj - 1)];
}

// small-angle double sincos (|x| <~ 0.7), libm fallback — IDENTICAL to round 2
__device__ __forceinline__ void sincos_small(double x, double* s, double* c) {
    double x2 = x * x;
    if (x2 > 0.49) { *s = sin(x); *c = cos(x); return; }
    *s = x * (1.0 + x2 * (-1.6666666666666666e-1 + x2 * (8.3333333333333333e-3 +
         x2 * (-1.9841269841269841e-4 + x2 * (2.7557319223985893e-6 - x2 * 2.5052108385441720e-8)))));
    *c = 1.0 + x2 * (-0.5 + x2 * (4.1666666666666666e-2 + x2 * (-1.3888888888888889e-3 +
         x2 * (2.4801587301587302e-5 - x2 * 2.7557319223985893e-7))));
}

// fp64 trig + fp32 bicubic tail shared by both snipers; writes out[idx].
__device__ __forceinline__ void snipe_tail(double u, double v, double dt,
                                           double phi_s, double phi_c, double lam,
                                           const float* __restrict__ plane,
                                           float* __restrict__ outp)
{
    const double TWO_PI = 6.2831853071795864769252867665590;
    const double PI_D   = 3.1415926535897932384626433832795;

    double lonp = -u * dt, latp = -v * dt;
    double slp, clp, slo, clo;
    sincos_small(latp, &slp, &clp);
    sincos_small(lonp, &slo, &clo);

    double sinlat = slp * phi_c + clp * clo * phi_s;
    sinlat = fmin(fmax(sinlat, -1.0 + 1e-7), 1.0 - 1e-7);
    double lat_dep = asin(sinlat);

    double num = clp * slo;
    double den = clp * clo * phi_c - slp * phi_s;
    double lon_dep = lam + atan2(num, den);
    double xr = lon_dep + TWO_PI;
    xr = xr - floor(xr / TWO_PI) * TWO_PI;

    double gx = (xr / TWO_PI * 2.0 - 1.0) * (480.0 / 482.0);
    double gy = (lat_dep / PI_D * 2.0 - 1.0) * (240.0 / 242.0);
    double ixd = fmin(fmax((gx + 1.0) * 0.5 * 481.0, 0.0), 481.0);
    double iyd = fmin(fmax((gy + 1.0) * 0.5 * 241.0, 0.0), 241.0);

    double x0d = floor(ixd), y0d = floor(iyd);
    float fx = (float)(ixd - x0d), fy = (float)(iyd - y0d);
    int x0 = (int)x0d, y0 = (int)y0d;

    const float a = -0.75f;
    float wx[4], wy[4];
    {
        float t = fx;
        float t1 = 1.f + t, t2 = 2.f - t, s1 = 1.f - t;
        wx[0] = ((a * t1 - 5.f * a) * t1 + 8.f * a) * t1 - 4.f * a;
        wx[1] = ((a + 2.f) * t - (a + 3.f)) * t * t + 1.f;
        wx[2] = ((a + 2.f) * s1 - (a + 3.f)) * s1 * s1 + 1.f;
        wx[3] = ((a * t2 - 5.f * a) * t2 + 8.f * a) * t2 - 4.f * a;
        t = fy;
        t1 = 1.f + t; t2 = 2.f - t; s1 = 1.f - t;
        wy[0] = ((a * t1 - 5.f * a) * t1 + 8.f * a) * t1 - 4.f * a;
        wy[1] = ((a + 2.f) * t - (a + 3.f)) * t * t + 1.f;
        wy[2] = ((a + 2.f) * s1 - (a + 3.f)) * s1 * s1 + 1.f;
        wy[3] = ((a * t2 - 5.f * a) * t2 + 8.f * a) * t2 - 4.f * a;
    }
    float accv = 0.f;
    #pragma unroll
    for (int i = 0; i < 4; i++) {
        int yi = min(max(y0 + i - 1, 0), 241);
        float row = 0.f;
        #pragma unroll
        for (int j = 0; j < 4; j++) {
            int xj = min(max(x0 + j - 1, 0), 481);
            row = fmaf(wx[j], padfetch(plane, yi, xj), row);
        }
        accv = fmaf(wy[i], row, accv);
    }
    *outp = accv;
}

// ---------------------------------------------------------------------------
// split weights [N][Kk] fp32 -> 3 bf16 planes [p][N][Kk]
// ---------------------------------------------------------------------------
__global__ void split_w(const float* __restrict__ w, u16* __restrict__ sp, int total) {
    int i = blockIdx.x * 256 + threadIdx.x;
    if (i >= total) return;
    float x = w[i];
    u16 a = f2bf(x); float r1 = x - bf2f(a);
    u16 b = f2bf(r1); float r2 = r1 - bf2f(b);
    sp[i] = a; sp[total + i] = b; sp[2 * total + i] = f2bf(r2);
}

// ---------------------------------------------------------------------------
// MFMA implicit-GEMM conv (bf16x3, 6-pass). UNCHANGED from round 7 (bit-exact).
// ---------------------------------------------------------------------------
template<int NN>
__global__ __launch_bounds__(256)
void conv_mfma(const float* __restrict__ in,     // [Cc][HW] batch plane
               const u16*  __restrict__ wsp,     // [3][NN][Kk] bf16 planes
               const float* __restrict__ bias,   // [NN]
               float* __restrict__ out)          // [NN][HW]
{
    constexpr int NT = NN / 32;                  // n-tiles per wave
    __shared__ short Al[3][128][40];             // [plane][m][k] rows padded to 80B
    __shared__ short Bl[3][NN][40];              // [plane][n][k]

    const int tid  = threadIdx.x;
    const int lane = tid & 63;
    const int wave = tid >> 6;
    const int wm = wave & 1, wn = wave >> 1;
    const int lr = lane & 15, kg = lane >> 4;
    const int m0 = blockIdx.x * 128;

    const int ms = tid & 127;
    const int ks = (tid >> 7) * 16;
    const int gm = m0 + ms;
    const int h = gm / Ww, w = gm - h * Ww;
    int sidx[9];
    #pragma unroll
    for (int q = 0; q < 9; q++) sidx[q] = geo_sidx(h + q / 3 - 1, w + q % 3 - 1);

    f32x4 acc[4][NT] = {};

    for (int kt = 0; kt < Kk; kt += 32) {
        __syncthreads();
        // ---- stage A: fp32 gather -> bf16x3 split -> LDS ----
        {
            int k = kt + ks;
            int ic = k / 9, t9 = k - ic * 9;
            short hh[3][16];
            #pragma unroll
            for (int j = 0; j < 16; j++) {
                float x = in[ic * HW + sidx[t9]];
                u16 a = f2bf(x); float r1 = x - bf2f(a);
                u16 b = f2bf(r1); float r2 = r1 - bf2f(b);
                hh[0][j] = (short)a; hh[1][j] = (short)b; hh[2][j] = (short)f2bf(r2);
                if (++t9 == 9) { t9 = 0; ic++; }
            }
            #pragma unroll
            for (int p = 0; p < 3; p++) {
                bf16x8 v0, v1;
                #pragma unroll
                for (int j = 0; j < 8; j++) { v0[j] = hh[p][j]; v1[j] = hh[p][8 + j]; }
                *(bf16x8*)&Al[p][ms][ks]     = v0;
                *(bf16x8*)&Al[p][ms][ks + 8] = v1;
            }
        }
        // ---- stage B: pre-split planes, coalesced 16B chunks ----
        {
            constexpr int NCH = 3 * NN * 4 / 256;
            #pragma unroll
            for (int cg = 0; cg < NCH; cg++) {
                int chunk = tid + cg * 256;
                int p = chunk / (NN * 4);
                int rem = chunk - p * NN * 4;
                int n = rem >> 2, part = rem & 3;
                bf16x8 v = *(const bf16x8*)&wsp[(size_t)(p * NN + n) * Kk + kt + part * 8];
                *(bf16x8*)&Bl[p][n][part * 8] = v;
            }
        }
        __syncthreads();
        // ---- 6 passes grouped by B plane: (pa,pb) with pa+pb<=2 ----
        #pragma unroll
        for (int pb = 0; pb < 3; pb++) {
            bf16x8 bq[NT];
            #pragma unroll
            for (int nt = 0; nt < NT; nt++)
                bq[nt] = *(const bf16x8*)&Bl[pb][wn * (NN / 2) + nt * 16 + lr][kg * 8];
            #pragma unroll
            for (int pa = 0; pa < 3 - pb; pa++) {
                #pragma unroll
                for (int mt = 0; mt < 4; mt++) {
                    bf16x8 af = *(const bf16x8*)&Al[pa][wm * 64 + mt * 16 + lr][kg * 8];
                    #pragma unroll
                    for (int nt = 0; nt < NT; nt++)
                        acc[mt][nt] = __builtin_amdgcn_mfma_f32_16x16x32_bf16(
                            af, bq[nt], acc[mt][nt], 0, 0, 0);
                }
            }
        }
    }
    #pragma unroll
    for (int mt = 0; mt < 4; mt++) {
        int mbase = m0 + wm * 64 + mt * 16 + kg * 4;
        #pragma unroll
        for (int nt = 0; nt < NT; nt++) {
            int n = wn * (NN / 2) + nt * 16 + lr;
            float bv = bias[n];
            float4 o;
            o.x = acc[mt][nt][0] + bv;
            o.y = acc[mt][nt][1] + bv;
            o.z = acc[mt][nt][2] + bv;
            o.w = acc[mt][nt][3] + bv;
            *(float4*)&out[(size_t)n * HW + mbase] = o;
        }
    }
}

// ---------------------------------------------------------------------------
// deterministic two-stage LayerNorm stats (unchanged)
// ---------------------------------------------------------------------------
__global__ __launch_bounds__(256)
void reduce_stats(const float* __restrict__ y, float* __restrict__ part) {
    const int n4 = (Cc * HW) / 4;
    float s = 0.f, ss = 0.f;
    for (int i = blockIdx.x * 256 + threadIdx.x; i < n4; i += NB_RED * 256) {
        float4 v = ((const float4*)y)[i];
        s  += v.x + v.y + v.z + v.w;
        ss += v.x * v.x + v.y * v.y + v.z * v.z + v.w * v.w;
    }
    #pragma unroll
    for (int o = 32; o > 0; o >>= 1) { s += __shfl_down(s, o); ss += __shfl_down(ss, o); }
    __shared__ float ls[4], lss[4];
    int wid = threadIdx.x >> 6, lane = threadIdx.x & 63;
    if (lane == 0) { ls[wid] = s; lss[wid] = ss; }
    __syncthreads();
    if (threadIdx.x == 0) {
        part[blockIdx.x * 2]     = ls[0] + ls[1] + ls[2] + ls[3];
        part[blockIdx.x * 2 + 1] = lss[0] + lss[1] + lss[2] + lss[3];
    }
}

__global__ __launch_bounds__(256)
void finalize_stats(const float* __restrict__ part, float* __restrict__ stats) {
    float s = 0.f, ss = 0.f;
    for (int i = threadIdx.x; i < NB_RED; i += 256) { s += part[2 * i]; ss += part[2 * i + 1]; }
    #pragma unroll
    for (int o = 32; o > 0; o >>= 1) { s += __shfl_down(s, o); ss += __shfl_down(ss, o); }
    __shared__ float ls[4], lss[4];
    int wid = threadIdx.x >> 6, lane = threadIdx.x & 63;
    if (lane == 0) { ls[wid] = s; lss[wid] = ss; }
    __syncthreads();
    if (threadIdx.x == 0) {
        stats[0] = ls[0] + ls[1] + ls[2] + ls[3];
        stats[1] = lss[0] + lss[1] + lss[2] + lss[3];
    }
}

__global__ void norm_silu(float* __restrict__ y, const float* __restrict__ g,
                          const float* __restrict__ bb, const float* __restrict__ stats) {
    int i = blockIdx.x * 256 + threadIdx.x;
    if (i >= Cc * HW) return;
    const float invN = 1.f / (float)(Cc * HW);
    float mu  = stats[0] * invN;
    float var = stats[1] * invN - mu * mu;
    float inv = rsqrtf(var + 1e-5f);
    float z = (y[i] - mu) * inv * g[i] + bb[i];
    y[i] = z / (1.f + expf(-z));
}

// ---------------------------------------------------------------------------
// semilag fast path (pure fp32). Pole rows (0,1,238,239) are NOT gated here —
// sniper_rows overwrites them unconditionally. Other rows enqueue on the
// r2 / sinlat / seam triggers only.
// ---------------------------------------------------------------------------
__global__ __launch_bounds__(256)
void semilag(const float* __restrict__ vel, const float* __restrict__ hid,
             const float* __restrict__ latg, const float* __restrict__ lng,
             const float* __restrict__ dtp, float* __restrict__ out,
             u32* __restrict__ wl, u32* __restrict__ wlcnt)
{
    int idx = blockIdx.x * 256 + threadIdx.x;
    if (idx >= Cc * HW) return;
    int c = idx / HW;
    int m = idx - c * HW;

    const float PI2F = 6.28318530717958647692f;

    float uf = vel[idx];
    float vf = vel[Cc * HW + idx];
    float dtf = dtp[0];
    float phi = latg[m], lam = lng[m];
    float sphi = sinf(phi), cphi = cosf(phi);

    float lonp = -uf * dtf, latp = -vf * dtf;
    float slp = sinf(latp), clp = cosf(latp);
    float slo = sinf(lonp), clo = cosf(lonp);
    float sinlat = slp * cphi + clp * clo * sphi;
    float num = clp * slo;
    float den = clp * clo * cphi - slp * sphi;
    float r2 = num * num + den * den;

    float lon_w = lam + atan2f(num, den) + PI2F;
    lon_w = lon_w - floorf(lon_w / PI2F) * PI2F;
    float seam = fminf(lon_w, PI2F - lon_w);

    bool pole = (m < 2 * Ww) | (m >= HW - 2 * Ww);
    bool snipe = !pole & ((r2 < 1e-4f) | (fabsf(sinlat) > 1.f - 1e-5f) | (seam < 1e-3f));
    if (snipe) {
        u32 s = atomicAdd(wlcnt, 1u);
        if (s < WLCAP) wl[s] = (u32)idx;
    }

    float sl = fminf(fmaxf(sinlat, -1.f + 1e-7f), 1.f - 1e-7f);
    float lat_dep = asinf(sl);
    float gx = (lon_w / PI2F * 2.f - 1.f) * (480.f / 482.f);
    float gy = (lat_dep / 3.14159265358979323846f * 2.f - 1.f) * (240.f / 242.f);
    double ixd = (double)fminf(fmaxf((gx + 1.f) * 0.5f * 481.f, 0.f), 481.f);
    double iyd = (double)fminf(fmaxf((gy + 1.f) * 0.5f * 241.f, 0.f), 241.f);

    double x0d = floor(ixd), y0d = floor(iyd);
    float fx = (float)(ixd - x0d), fy = (float)(iyd - y0d);
    int x0 = (int)x0d, y0 = (int)y0d;

    const float a = -0.75f;
    float wx[4], wy[4];
    {
        float t = fx;
        float t1 = 1.f + t, t2 = 2.f - t, s1 = 1.f - t;
        wx[0] = ((a * t1 - 5.f * a) * t1 + 8.f * a) * t1 - 4.f * a;
        wx[1] = ((a + 2.f) * t - (a + 3.f)) * t * t + 1.f;
        wx[2] = ((a + 2.f) * s1 - (a + 3.f)) * s1 * s1 + 1.f;
        wx[3] = ((a * t2 - 5.f * a) * t2 + 8.f * a) * t2 - 4.f * a;
        t = fy;
        t1 = 1.f + t; t2 = 2.f - t; s1 = 1.f - t;
        wy[0] = ((a * t1 - 5.f * a) * t1 + 8.f * a) * t1 - 4.f * a;
        wy[1] = ((a + 2.f) * t - (a + 3.f)) * t * t + 1.f;
        wy[2] = ((a + 2.f) * s1 - (a + 3.f)) * s1 * s1 + 1.f;
        wy[3] = ((a * t2 - 5.f * a) * t2 + 8.f * a) * t2 - 4.f * a;
    }

    const float* plane = hid + (size_t)c * HW;
    float accv = 0.f;
    #pragma unroll
    for (int i = 0; i < 4; i++) {
        int yi = min(max(y0 + i - 1, 0), 241);
        float row = 0.f;
        #pragma unroll
        for (int j = 0; j < 4; j++) {
            int xj = min(max(x0 + j - 1, 0), 481);
            row = fmaf(wx[j], padfetch(plane, yi, xj), row);
        }
        accv = fmaf(wy[i], row, accv);
    }
    out[idx] = accv;
}

// ---------------------------------------------------------------------------
// sniper_rows: pole rows {0,1,238,239} — one block per spatial pixel.
// Gather x[1152] to LDS once; 256 threads each do one exact fp64 dot
// (all u,v channels); threads 0..127 run the fp64 trig + bicubic.
// ---------------------------------------------------------------------------
__global__ __launch_bounds__(256)
void sniper_rows(const float* __restrict__ y1, const float* __restrict__ w2,
                 const float* __restrict__ b2, const float* __restrict__ hid,
                 const float* __restrict__ latg, const float* __restrict__ lng,
                 const float* __restrict__ dtp, float* __restrict__ out)
{
    __shared__ float xl[Kk];
    __shared__ double resd[256];

    const int tid = threadIdx.x;
    const int ri  = blockIdx.x / Ww;
    const int col = blockIdx.x - ri * Ww;
    const int r   = (ri < 2) ? ri : (236 + ri);   // 0,1,238,239
    const int m   = r * Ww + col;

    for (int k = tid; k < Kk; k += 256) {
        int ic = k / 9, t9 = k - ic * 9;
        xl[k] = y1[ic * HW + geo_sidx(r + t9 / 3 - 1, col + t9 % 3 - 1)];
    }
    __syncthreads();

    // one fp64 dot per thread (och = tid: rows of w2), 4-way ILP
    {
        const float* wrow = w2 + (size_t)tid * Kk;
        double a0 = 0.0, a1 = 0.0, a2 = 0.0, a3 = 0.0;
        #pragma unroll 4
        for (int k = 0; k < Kk; k += 4) {
            a0 = fma((double)wrow[k],     (double)xl[k],     a0);
            a1 = fma((double)wrow[k + 1], (double)xl[k + 1], a1);
            a2 = fma((double)wrow[k + 2], (double)xl[k + 2], a2);
            a3 = fma((double)wrow[k + 3], (double)xl[k + 3], a3);
        }
        resd[tid] = (a0 + a1) + (a2 + a3);
    }
    __syncthreads();

    if (tid < Cc) {
        double u = (double)b2[tid] + resd[tid];
        double v = (double)b2[Cc + tid] + resd[Cc + tid];
        double dt = (double)dtp[0];
        double phi = (double)latg[m];
        snipe_tail(u, v, dt, sin(phi), cos(phi), (double)lng[m],
                   hid + (size_t)tid * HW, &out[(size_t)tid * HW + m]);
    }
}

// ---------------------------------------------------------------------------
// sniper: per worklist entry (non-pole stragglers), one wave per entry.
// t9-outer loop -> sidx statically indexed (registers, no scratch).
// ---------------------------------------------------------------------------
__global__ __launch_bounds__(256)
void sniper(const u32* __restrict__ wl, const u32* __restrict__ wlcnt,
            const float* __restrict__ y1, const float* __restrict__ w2,
            const float* __restrict__ b2, const float* __restrict__ hid,
            const float* __restrict__ latg, const float* __restrict__ lng,
            const float* __restrict__ dtp, float* __restrict__ out)
{
    const int lane = threadIdx.x & 63;
    const int wavid = (blockIdx.x * 256 + threadIdx.x) >> 6;
    const int nwaves = gridDim.x * 4;
    int n = (int)*wlcnt; if (n > WLCAP) n = WLCAP;

    for (int e = wavid; e < n; e += nwaves) {
        u32 idx = wl[e];
        int c = idx / HW, m = idx - c * HW;
        int h = m / Ww, w = m - h * Ww;

        double su = 0.0, sv = 0.0;
        const float* wu = w2 + (size_t)c * Kk;
        const float* wv = w2 + (size_t)(Cc + c) * Kk;
        #pragma unroll
        for (int t9 = 0; t9 < 9; t9++) {
            int s = geo_sidx(h + t9 / 3 - 1, w + t9 % 3 - 1);
            #pragma unroll
            for (int q = 0; q < 2; q++) {
                int ic = q * 64 + lane;
                int k = ic * 9 + t9;
                double yv = (double)y1[ic * HW + s];
                su = fma((double)wu[k], yv, su);
                sv = fma((double)wv[k], yv, sv);
            }
        }
        #pragma unroll
        for (int o = 32; o > 0; o >>= 1) {
            su += __shfl_down(su, o);
            sv += __shfl_down(sv, o);
        }
        if (lane == 0) {
            double u = (double)b2[c] + su;
            double v = (double)b2[Cc + c] + sv;
            double dt = (double)dtp[0];
            double phi = (double)latg[m];
            snipe_tail(u, v, dt, sin(phi), cos(phi), (double)lng[m],
                       hid + (size_t)c * HW, &out[idx]);
        }
    }
}

// ---------------------------------------------------------------------------
extern "C" void kernel_launch(void* const* d_in, const int* in_sizes, int n_in,
                              void* d_out, int out_size, void* d_ws, size_t ws_size,
                              hipStream_t stream)
{
    const float* hidden = (const float*)d_in[0];
    const float* latg   = (const float*)d_in[1];
    const float* lng    = (const float*)d_in[2];
    const float* w1     = (const float*)d_in[3];
    const float* b1     = (const float*)d_in[4];
    const float* g      = (const float*)d_in[5];
    const float* lb     = (const float*)d_in[6];
    const float* w2     = (const float*)d_in[7];
    const float* b2     = (const float*)d_in[8];
    const float* dt     = (const float*)d_in[9];
    float* out = (float*)d_out;

    float* ws    = (float*)d_ws;
    float* stats = ws;
    float* part  = ws + 4;
    u32*   wlcnt = (u32*)(ws + 4 + 2 * NB_RED);
    u16*   wsp1  = (u16*)(ws + 4 + 2 * NB_RED + 4);
    u16*   wsp2  = wsp1 + (size_t)3 * Cc * Kk;
    float* y1    = (float*)(wsp2 + (size_t)3 * 2 * Cc * Kk);
    float* vel   = y1 + (size_t)Cc * HW;
    u32*   wl    = (u32*)(vel + (size_t)2 * Cc * HW);

    split_w<<<(Cc * Kk + 255) / 256, 256, 0, stream>>>(w1, wsp1, Cc * Kk);
    split_w<<<(2 * Cc * Kk + 255) / 256, 256, 0, stream>>>(w2, wsp2, 2 * Cc * Kk);

    for (int b = 0; b < 2; b++) {
        const float* hb = hidden + (size_t)b * Cc * HW;
        const float* lab = latg + (size_t)b * HW;
        const float* lob = lng + (size_t)b * HW;
        float* ob = out + (size_t)b * Cc * HW;

        conv_mfma<128><<<HW / 128, 256, 0, stream>>>(hb, wsp1, b1, y1);
        reduce_stats<<<NB_RED, 256, 0, stream>>>(y1, part);
        finalize_stats<<<1, 256, 0, stream>>>(part, stats + 2 * b);
        norm_silu<<<(Cc * HW) / 256, 256, 0, stream>>>(y1, g, lb, stats + 2 * b);
        conv_mfma<256><<<HW / 128, 256, 0, stream>>>(y1, wsp2, b2, vel);
        hipMemsetAsync(wlcnt, 0, 4, stream);
        semilag<<<(Cc * HW) / 256, 256, 0, stream>>>(vel, hb, lab, lob, dt, ob, wl, wlcnt);
        sniper_rows<<<4 * Ww, 256, 0, stream>>>(y1, w2, b2, hb, lab, lob, dt, ob);
        sniper<<<2048, 256, 0, stream>>>(wl, wlcnt, y1, w2, b2, hb, lab, lob, dt, ob);
    }
}